// Round 10
// baseline (113.514 us; speedup 1.0000x reference)
//
#include <hip/hip_runtime.h>
#include <hip/hip_fp16.h>

#define DEVI __device__ __forceinline__

typedef float f32x4 __attribute__((ext_vector_type(4)));
typedef float float4v __attribute__((ext_vector_type(4)));
typedef _Float16 f16x8 __attribute__((ext_vector_type(8)));
typedef unsigned short us8 __attribute__((ext_vector_type(8)));

constexpr int NB = 32, TC = 2048, TQ = 256, DD = 256;
constexpr int CR = 64;                      // c-rows per tile
constexpr float VNEG = -1e29f;

DEVI unsigned short f2h(float f) {
  _Float16 h = (_Float16)f;                 // v_cvt_f16_f32 (RN)
  return __builtin_bit_cast(unsigned short, h);
}
DEVI float h2f(unsigned short u) {
  return (float)__builtin_bit_cast(_Float16, u);
}

// XOR swizzle on 16B granules within a 512B row; involution (write==read).
DEVI int swz(int row, int cb) { return cb ^ (((row ^ (cb >> 7)) & 7) << 4); }

DEVI f32x4 mfmah(us8 a, us8 b, f32x4 c) {
  return __builtin_amdgcn_mfma_f32_16x16x32_f16(
      __builtin_bit_cast(f16x8, a), __builtin_bit_cast(f16x8, b), c, 0, 0, 0);
}

// ---------------------------------------------------------------------------
// P0: one pass over Q producing Qh (fp16 row-major) AND QT (fp16 transposed).
// 512 blocks: one 64x64 tile each.
// ---------------------------------------------------------------------------
__global__ void P0(const float* __restrict__ Qg, unsigned short* __restrict__ Qh,
                   unsigned short* __restrict__ QT)
{
  __shared__ unsigned short t[64][72];
  const int bid = blockIdx.x, tid = threadIdx.x;
  const int b = bid >> 4;
  const int q0 = ((bid >> 2) & 3) * 64, d0 = (bid & 3) * 64;
  {
    const int qr = tid >> 2, dp = (tid & 3) * 16;
    const float* src = Qg + ((size_t)b * TQ + q0 + qr) * DD + d0 + dp;
    unsigned short* dst = Qh + ((size_t)b * TQ + q0 + qr) * DD + d0 + dp;
    us8 o0, o1;
#pragma unroll
    for (int i = 0; i < 4; ++i) {
      float4v v = *(const float4v*)(src + i * 4);
#pragma unroll
      for (int j = 0; j < 4; ++j) {
        const unsigned short h = f2h(v[j]);
        t[qr][dp + i * 4 + j] = h;
        if (i < 2) o0[i * 4 + j] = h; else o1[(i - 2) * 4 + j] = h;
      }
    }
    *(us8*)dst = o0;
    *(us8*)(dst + 8) = o1;
  }
  __syncthreads();
  {
    const int dr = tid >> 2, qp = (tid & 3) * 16;
    us8 a, c;
#pragma unroll
    for (int i = 0; i < 8; ++i) a[i] = t[qp + i][dr];
#pragma unroll
    for (int i = 0; i < 8; ++i) c[i] = t[qp + 8 + i][dr];
    unsigned short* dst = QT + ((size_t)b * DD + d0 + dr) * TQ + q0 + qp;
    *(us8*)dst = a;
    *(us8*)(dst + 8) = c;
  }
}

// ---------------------------------------------------------------------------
// Kernel A: grid 512 (= 256 CU x 2 blocks, ONE residence round). Each block
// processes TWO 64-row c-tiles; tile1's C is loaded into registers during
// tile0's softmax and written to a second LDS buffer before tile0's last
// barrier, so tile1 starts with no staging phase. Q/QT fragments batched
// into registers (16-deep MLP); qt split 8+8 to fit the 128-reg budget.
// ---------------------------------------------------------------------------
__global__ __launch_bounds__(512, 4)
void kA(const float* __restrict__ Cg, const unsigned short* __restrict__ Qh,
        const unsigned short* __restrict__ QT,
        const int* __restrict__ clenp, const int* __restrict__ qlenp,
        float* __restrict__ out1, float* __restrict__ pnum,
        float* __restrict__ ptM, float* __restrict__ ptD)
{
  __shared__ __align__(16) char lds0[32768];   // tile0 C, later tile0 P
  __shared__ __align__(16) char lds1[32768];   // tile1 C, later tile1 P
  __shared__ float redM[512];                  // per-wave row maxima
  __shared__ float redS[512];                  // per-wave row sums
  __shared__ float wred[64];                   // global row max M_c
  __shared__ float wexp[64];                   // exp(M_c - mtile)
  __shared__ float sinv[64];                   // 1 / row softmax sum

  const int bid = blockIdx.x;                  // 0..511
  const int b = bid & 31;                      // batch -> fixed XCD (bid%8==b%8)
  const int slot = bid >> 5;                   // 0..15
  const int tid = threadIdx.x;
  const int l = tid & 63, wid = tid >> 6;      // 8 waves
  const int g = l >> 4, lm = l & 15;
  const int clen = clenp[b], qlen = qlenp[b];

  const unsigned short* Qhb = Qh + (size_t)b * TQ * DD;
  const unsigned short* QTb = QT + (size_t)b * DD * TQ;

  const int r_st = tid >> 3;                   // staging row (64 rows, 8 thr/row)
  const int d_st = (tid & 7) * 32;             // staging d base

#pragma unroll
  for (int t = 0; t < 2; ++t) {
    const int tile = slot * 2 + t;
    const int c0 = tile * CR;
    char* const bufC = t ? lds1 : lds0;        // P aliases the same buffer

    if (t == 1) asm volatile("" ::: "memory"); // block CSE of bq/qt reloads

    // ---- preload ALL sim Q fragments (16 x us8 = 64 VGPR, 16-deep MLP) ----
    us8 bq[16];
#pragma unroll
    for (int kk = 0; kk < 8; ++kk)
#pragma unroll
      for (int nt = 0; nt < 2; ++nt)
        bq[kk * 2 + nt] = *(const us8*)(Qhb +
            (size_t)(wid * 32 + nt * 16 + lm) * DD + kk * 32 + g * 8);

    if (t == 0) {
      // ---- stage tile0 C: 64 x 256 fp32 -> fp16 LDS (latency hides bq) ----
      const float* src = Cg + (size_t)(b * TC + c0 + r_st) * DD + d_st;
#pragma unroll
      for (int i = 0; i < 4; ++i) {
        us8 h;
#pragma unroll
        for (int k = 0; k < 8; k += 4) {
          float4v v = *(const float4v*)(src + i * 8 + k);
#pragma unroll
          for (int j = 0; j < 4; ++j) h[k + j] = f2h(v[j]);
        }
        *(us8*)(bufC + r_st * 512 + swz(r_st, (d_st + i * 8) * 2)) = h;
      }
      __syncthreads();   // bar1 (tile0 C visible)
    }
    // t==1: lds1 was staged during tile0 and made visible by tile0's bar6.

    f32x4 acc[4][2];
#pragma unroll
    for (int mt = 0; mt < 4; ++mt)
#pragma unroll
      for (int nt = 0; nt < 2; ++nt) acc[mt][nt] = (f32x4)0.0f;

    // ---- sim: pure LDS + MFMA (Q already in registers) ----
#pragma unroll
    for (int kk = 0; kk < 8; ++kk) {
      us8 ah[4];
#pragma unroll
      for (int mt = 0; mt < 4; ++mt) {
        const int row = mt * 16 + lm;
        ah[mt] = *(const us8*)(bufC + row * 512 + swz(row, kk * 64 + g * 16));
      }
#pragma unroll
      for (int mt = 0; mt < 4; ++mt)
#pragma unroll
        for (int nt = 0; nt < 2; ++nt)
          acc[mt][nt] = mfmah(ah[mt], bq[kk * 2 + nt], acc[mt][nt]);
    }

    // ---- mask (exact fp32 absorption to -1e29, as reference) ----
#pragma unroll
    for (int nt = 0; nt < 2; ++nt) {
      const int q = wid * 32 + nt * 16 + lm;
      const bool qm = q >= qlen;
#pragma unroll
      for (int mt = 0; mt < 4; ++mt)
#pragma unroll
        for (int j = 0; j < 4; ++j) {
          const int c = c0 + mt * 16 + g * 4 + j;
          if (qm || c >= clen) acc[mt][nt][j] = VNEG;
        }
    }

    // ---- per-wave row maxima -> redM ----
#pragma unroll
    for (int mt = 0; mt < 4; ++mt)
#pragma unroll
      for (int j = 0; j < 4; ++j) {
        float m = fmaxf(acc[mt][0][j], acc[mt][1][j]);
        m = fmaxf(m, __shfl_xor(m, 1, 64));
        m = fmaxf(m, __shfl_xor(m, 2, 64));
        m = fmaxf(m, __shfl_xor(m, 4, 64));
        m = fmaxf(m, __shfl_xor(m, 8, 64));
        if (lm == 0) redM[wid * 64 + mt * 16 + g * 4 + j] = m;
      }
    __syncthreads();   // bar2 (redM complete; also fences prior-tile epilogue)

    // ---- global row maxima -> wred (first 64 threads) ----
    if (tid < 64) {
      float m = redM[tid];
#pragma unroll
      for (int w = 1; w < 8; ++w) m = fmaxf(m, redM[w * 64 + tid]);
      wred[tid] = m;
    }
    __syncthreads();   // bar3 (wred visible)

    // ---- issue NEXT tile's C loads (bq is dead now; 32 VGPR) ----
    float4v cr[8];
    if (t == 0) {
      const float* src2 = Cg + (size_t)(b * TC + slot * 2 * CR + CR + r_st) * DD + d_st;
#pragma unroll
      for (int i = 0; i < 8; ++i) cr[i] = *(const float4v*)(src2 + i * 4);
    }

    // ---- exp + per-wave row sums -> redS (row max from LDS) ----
#pragma unroll
    for (int mt = 0; mt < 4; ++mt)
#pragma unroll
      for (int j = 0; j < 4; ++j) {
        const float m = wred[mt * 16 + g * 4 + j];
        float s = 0.f;
#pragma unroll
        for (int nt = 0; nt < 2; ++nt) {
          const float p = __expf(acc[mt][nt][j] - m);
          acc[mt][nt][j] = p;
          s += p;
        }
        s += __shfl_xor(s, 1, 64);
        s += __shfl_xor(s, 2, 64);
        s += __shfl_xor(s, 4, 64);
        s += __shfl_xor(s, 8, 64);
        if (lm == 0) redS[wid * 64 + mt * 16 + g * 4 + j] = s;
      }
    // ---- tile max + wexp + ptM/ptD (wave 0; wred stable after bar3) ----
    if (wid == 0) {
      float m = wred[l];
      m = fmaxf(m, __shfl_xor(m, 1, 64));  m = fmaxf(m, __shfl_xor(m, 2, 64));
      m = fmaxf(m, __shfl_xor(m, 4, 64));  m = fmaxf(m, __shfl_xor(m, 8, 64));
      m = fmaxf(m, __shfl_xor(m, 16, 64)); m = fmaxf(m, __shfl_xor(m, 32, 64));
      const float wv = __expf(wred[l] - m);
      wexp[l] = wv;
      float s = wv;
      s += __shfl_xor(s, 1, 64);  s += __shfl_xor(s, 2, 64);
      s += __shfl_xor(s, 4, 64);  s += __shfl_xor(s, 8, 64);
      s += __shfl_xor(s, 16, 64); s += __shfl_xor(s, 32, 64);
      if (l == 0) { ptD[b * 32 + tile] = s; ptM[b * 32 + tile] = m; }
    }
    __syncthreads();   // bar4 (redS + wexp visible)

    // ---- preload PV QT fragments, FIRST half (8 x us8 = 32 VGPR) ----
    us8 qt[16];
#pragma unroll
    for (int kq = 0; kq < 4; ++kq)
#pragma unroll
      for (int dt = 0; dt < 2; ++dt)
        qt[kq * 2 + dt] = *(const us8*)(QTb +
            (size_t)(wid * 32 + dt * 16 + lm) * TQ + kq * 32 + g * 8);

    // ---- per-row 1/sum -> sinv ----
    if (tid < 64) {
      float s = 0.f;
#pragma unroll
      for (int w = 0; w < 8; ++w) s += redS[w * 64 + tid];
      sinv[tid] = 1.0f / s;
    }

    // ---- q2c partial from LDS C-tile ----
    {
      const int half = tid >> 8;              // 0/1 -> rows 0..31 / 32..63
      const int d = tid & 255;
      float qacc = 0.f;
      const int d2 = d * 2;
#pragma unroll 8
      for (int r = half * 32; r < half * 32 + 32; ++r) {
        const float cv = h2f(*(const unsigned short*)(bufC + r * 512 + swz(r, d2)));
        qacc += wexp[r] * cv;
      }
      pnum[(((size_t)b * 32 + tile) * 2 + half) * DD + d] = qacc;
    }

    // ---- write staged tile1 C into lds1 (visible after bar6) ----
    if (t == 0) {
#pragma unroll
      for (int i = 0; i < 4; ++i) {
        us8 h;
#pragma unroll
        for (int j = 0; j < 4; ++j) h[j] = f2h(cr[2 * i][j]);
#pragma unroll
        for (int j = 0; j < 4; ++j) h[4 + j] = f2h(cr[2 * i + 1][j]);
        *(us8*)(lds1 + r_st * 512 + swz(r_st, (d_st + i * 8) * 2)) = h;
      }
    }
    __syncthreads();   // bar5 (bufC q2c reads done; safe to overwrite with P)

    // ---- write P (un-normalized exp, fp16) into bufC alias ----
#pragma unroll
    for (int mt = 0; mt < 4; ++mt)
#pragma unroll
      for (int nt = 0; nt < 2; ++nt)
#pragma unroll
        for (int j = 0; j < 4; ++j) {
          const int row = mt * 16 + g * 4 + j;
          const int cb = (wid * 32 + nt * 16 + lm) * 2;
          *(unsigned short*)(bufC + row * 512 + swz(row, cb)) = f2h(acc[mt][nt][j]);
        }
    __syncthreads();   // bar6 (P + tile1-C + sinv visible)

    // ---- preload PV QT fragments, SECOND half (hides under kq 0..3) ----
#pragma unroll
    for (int kq = 4; kq < 8; ++kq)
#pragma unroll
      for (int dt = 0; dt < 2; ++dt)
        qt[kq * 2 + dt] = *(const us8*)(QTb +
            (size_t)(wid * 32 + dt * 16 + lm) * TQ + kq * 32 + g * 8);

    // ---- PV: pure LDS + MFMA ----
    f32x4 pacc[4][2];
#pragma unroll
    for (int mt = 0; mt < 4; ++mt)
#pragma unroll
      for (int dt = 0; dt < 2; ++dt) pacc[mt][dt] = (f32x4)0.0f;
#pragma unroll
    for (int kq = 0; kq < 8; ++kq) {
      us8 pa[4];
#pragma unroll
      for (int mt = 0; mt < 4; ++mt) {
        const int row = mt * 16 + lm;
        pa[mt] = *(const us8*)(bufC + row * 512 + swz(row, kq * 64 + g * 16));
      }
#pragma unroll
      for (int mt = 0; mt < 4; ++mt)
#pragma unroll
        for (int dt = 0; dt < 2; ++dt)
          pacc[mt][dt] = mfmah(pa[mt], qt[kq * 2 + dt], pacc[mt][dt]);
    }

    // ---- epilogue: normalize (1/sum from LDS) and store ----
#pragma unroll
    for (int mt = 0; mt < 4; ++mt)
#pragma unroll
      for (int j = 0; j < 4; ++j) {
        const int row = mt * 16 + g * 4 + j;
        const float inv = sinv[row];
        const size_t rowoff = (size_t)(b * TC + c0 + row) * DD;
#pragma unroll
        for (int dt = 0; dt < 2; ++dt)
          out1[rowoff + wid * 32 + dt * 16 + lm] = pacc[mt][dt][j] * inv;
      }
  }
}

// ---------------------------------------------------------------------------
// kC (fused combine + broadcast): each block recomputes
//   q2c[b,d] = sum_t e^{ptM_t-m}(pnum[t,0,d]+pnum[t,1,d]) / sum_t e^{ptM_t-m} ptD_t
// then broadcasts into its 128-row segment of out2.
// ---------------------------------------------------------------------------
__global__ void kC(const float* __restrict__ pnum, const float* __restrict__ ptM,
                   const float* __restrict__ ptD, float* __restrict__ out2)
{
  const int b = blockIdx.x >> 4, seg = blockIdx.x & 15;
  const int d = threadIdx.x;
  __shared__ float sM[32], sD[32];
  if (d < 32) { sM[d] = ptM[b * 32 + d]; sD[d] = ptD[b * 32 + d]; }
  __syncthreads();
  float m = sM[0];
#pragma unroll
  for (int t = 1; t < 32; ++t) m = fmaxf(m, sM[t]);
  float den = 0.f, acc = 0.f;
#pragma unroll
  for (int t = 0; t < 32; ++t) {
    const float sc = __expf(sM[t] - m);
    den += sc * sD[t];
    const size_t base = (((size_t)b * 32 + t) * 2) * DD + d;
    acc += sc * (pnum[base] + pnum[base + DD]);
  }
  const float s = acc / den;
  float* dst = out2 + ((size_t)b * TC + seg * 128) * DD + d;
#pragma unroll 4
  for (int c = 0; c < 128; ++c) dst[(size_t)c * DD] = s;
}

extern "C" void kernel_launch(void* const* d_in, const int* in_sizes, int n_in,
                              void* d_out, int out_size, void* d_ws, size_t ws_size,
                              hipStream_t stream)
{
  const float* Cg = (const float*)d_in[0];
  const float* Qg = (const float*)d_in[1];
  const int* clen = (const int*)d_in[2];
  const int* qlen = (const int*)d_in[3];
  float* out1 = (float*)d_out;
  float* out2 = out1 + (size_t)NB * TC * DD;

  char* ws = (char*)d_ws;
  float* pnum = (float*)(ws);                          // 32*32*2*256 f32 = 2 MB
  float* ptM  = (float*)(ws + 2097152);                // 1024 f32
  float* ptD  = (float*)(ws + 2101248);                // 1024 f32
  unsigned short* Qh = (unsigned short*)(ws + 2105344);          // 4 MB
  unsigned short* QT = (unsigned short*)(ws + 2105344 + 4194304);// 4 MB

  P0 <<<dim3(512), dim3(256), 0, stream>>>(Qg, Qh, QT);
  kA <<<dim3(512), dim3(512), 0, stream>>>(Cg, Qh, QT, clen, qlen,
                                           out1, pnum, ptM, ptD);
  kC <<<dim3(NB * 16), dim3(256), 0, stream>>>(pnum, ptM, ptD, out2);
}

// Round 11
// 89.375 us; speedup vs baseline: 1.2701x; 1.2701x over previous
//
#include <hip/hip_runtime.h>
#include <hip/hip_fp16.h>

#define DEVI __device__ __forceinline__

typedef float f32x4 __attribute__((ext_vector_type(4)));
typedef float float4v __attribute__((ext_vector_type(4)));
typedef _Float16 f16x8 __attribute__((ext_vector_type(8)));
typedef unsigned short us8 __attribute__((ext_vector_type(8)));

constexpr int NB = 32, TC = 2048, TQ = 256, DD = 256;
constexpr int CR = 64;                      // c-rows per kA block
constexpr float VNEG = -1e29f;

DEVI unsigned short f2h(float f) {
  _Float16 h = (_Float16)f;                 // v_cvt_f16_f32 (RN)
  return __builtin_bit_cast(unsigned short, h);
}
DEVI float h2f(unsigned short u) {
  return (float)__builtin_bit_cast(_Float16, u);
}

// XOR swizzle on 16B granules within a 512B row; involution (write==read).
DEVI int swz(int row, int cb) { return cb ^ (((row ^ (cb >> 7)) & 7) << 4); }

DEVI f32x4 mfmah(us8 a, us8 b, f32x4 c) {
  return __builtin_amdgcn_mfma_f32_16x16x32_f16(
      __builtin_bit_cast(f16x8, a), __builtin_bit_cast(f16x8, b), c, 0, 0, 0);
}

// ---------------------------------------------------------------------------
// P0: blocks [0,512): Qh (fp16 row-major) + QT (fp16 transposed), 64x64 tiles.
//     blocks [512,544): qmean[b,d] = (1/256) * sum_q Q[b,q,d]  (fp32 exact path)
// ---------------------------------------------------------------------------
__global__ void P0(const float* __restrict__ Qg, unsigned short* __restrict__ Qh,
                   unsigned short* __restrict__ QT, float* __restrict__ qmean)
{
  __shared__ unsigned short t[64][72];
  const int bid = blockIdx.x, tid = threadIdx.x;
  if (bid < 512) {
    const int b = bid >> 4;
    const int q0 = ((bid >> 2) & 3) * 64, d0 = (bid & 3) * 64;
    {
      const int qr = tid >> 2, dp = (tid & 3) * 16;
      const float* src = Qg + ((size_t)b * TQ + q0 + qr) * DD + d0 + dp;
      unsigned short* dst = Qh + ((size_t)b * TQ + q0 + qr) * DD + d0 + dp;
      us8 o0, o1;
#pragma unroll
      for (int i = 0; i < 4; ++i) {
        float4v v = *(const float4v*)(src + i * 4);
#pragma unroll
        for (int j = 0; j < 4; ++j) {
          const unsigned short h = f2h(v[j]);
          t[qr][dp + i * 4 + j] = h;
          if (i < 2) o0[i * 4 + j] = h; else o1[(i - 2) * 4 + j] = h;
        }
      }
      *(us8*)dst = o0;
      *(us8*)(dst + 8) = o1;
    }
    __syncthreads();
    {
      const int dr = tid >> 2, qp = (tid & 3) * 16;
      us8 a, c;
#pragma unroll
      for (int i = 0; i < 8; ++i) a[i] = t[qp + i][dr];
#pragma unroll
      for (int i = 0; i < 8; ++i) c[i] = t[qp + 8 + i][dr];
      unsigned short* dst = QT + ((size_t)b * DD + d0 + dr) * TQ + q0 + qp;
      *(us8*)dst = a;
      *(us8*)(dst + 8) = c;
    }
  } else {
    const int b = bid - 512;                // 0..31
    const float* src = Qg + (size_t)b * TQ * DD + tid;
    float s = 0.f;
#pragma unroll 8
    for (int q = 0; q < TQ; ++q) s += src[(size_t)q * DD];
    qmean[b * DD + tid] = s * (1.0f / 256.0f);
  }
}

// ---------------------------------------------------------------------------
// Kernel A: per (batch, 64-row c-tile), 512 threads = 8 waves.
// FAST PATH (c0 >= clen): rows are fully masked -> out1 rows = qmean (exact),
// pnum = 0, ptM = -1e29, ptD = 0; no C load / sim / softmax / PV.
// VALID PATH: waves with fully-masked q-strips skip sim; PV truncated at
// kqmax = ceil(qlen/32) (P == 0 beyond, exactly); rows >= clen overwritten
// with qmean in the epilogue.
// ---------------------------------------------------------------------------
__global__ __launch_bounds__(512, 6)
void kA(const float* __restrict__ Cg, const unsigned short* __restrict__ Qh,
        const unsigned short* __restrict__ QT, const float* __restrict__ qmean,
        const int* __restrict__ clenp, const int* __restrict__ qlenp,
        float* __restrict__ out1, float* __restrict__ pnum,
        float* __restrict__ ptM, float* __restrict__ ptD)
{
  __shared__ __align__(16) char lds[32768];  // bufC (fp16), later bufP
  __shared__ float redM[512];                // per-wave row maxima
  __shared__ float redS[512];                // per-wave row sums
  __shared__ float wred[64];                 // global row max M_c
  __shared__ float wexp[64];                 // exp(M_c - mtile)
  __shared__ float sinv[64];                 // 1 / row softmax sum
  char* const bufC = lds;
  char* const bufP = lds;

  const int bid = blockIdx.x;
  const int b = bid >> 5;                    // batch (tiles spread over XCDs)
  const int tile = bid & 31;                 // 0..31
  const int c0 = tile * CR;
  const int tid = threadIdx.x;
  const int clen = clenp[b], qlen = qlenp[b];

  // ================= FAST PATH: fully-masked tile =================
  if (c0 >= clen) {
    // out1 rows c0..c0+63 = qmean[b,:] (reference: uniform softmax over all q)
    const int r = tid >> 3;                  // 64 rows, 8 threads/row
    const int d0 = (tid & 7) * 32;
    const float* qm = qmean + b * DD + d0;
    float4v v[8];
#pragma unroll
    for (int i = 0; i < 8; ++i) v[i] = *(const float4v*)(qm + i * 4);
    float* dst = out1 + (size_t)(b * TC + c0 + r) * DD + d0;
#pragma unroll
    for (int i = 0; i < 8; ++i) *(float4v*)(dst + i * 4) = v[i];
    // pnum = 0 (its kComb weight is exp(-1e29 - m) = 0)
    pnum[(((size_t)b * 32 + tile) * 2 + (tid >> 8)) * DD + (tid & 255)] = 0.f;
    if (tid == 0) { ptM[b * 32 + tile] = VNEG; ptD[b * 32 + tile] = 0.f; }
    return;
  }

  // ================= VALID PATH =================
  const int l = tid & 63, wid = tid >> 6;    // 8 waves
  const int g = l >> 4, lm = l & 15;
  const bool wq_active = (wid * 32 < qlen);  // wave's q-strip has live columns
  const int kqmax = (qlen + 31) >> 5;        // PV q-chunks needed

  const unsigned short* Qhb = Qh + (size_t)b * TQ * DD;
  const unsigned short* QTb = QT + (size_t)b * DD * TQ;

  // ---- stage C tile once: 64 rows x 256 d fp32 -> fp16 LDS ----
  {
    const int r = tid >> 3;                  // 64 rows, 8 threads/row
    const int d0 = (tid & 7) * 32;
    const float* src = Cg + (size_t)(b * TC + c0 + r) * DD + d0;
#pragma unroll
    for (int i = 0; i < 4; ++i) {
      us8 h;
#pragma unroll
      for (int k = 0; k < 8; k += 4) {
        float4v v = *(const float4v*)(src + i * 8 + k);
#pragma unroll
        for (int j = 0; j < 4; ++j) h[k + j] = f2h(v[j]);
      }
      *(us8*)(bufC + r * 512 + swz(r, (d0 + i * 8) * 2)) = h;
    }
  }
  __syncthreads();   // bar1

  f32x4 acc[4][2];
#pragma unroll
  for (int mt = 0; mt < 4; ++mt)
#pragma unroll
    for (int nt = 0; nt < 2; ++nt) acc[mt][nt] = (f32x4)0.0f;

  // ---- sim (skipped entirely for fully-masked q-strips) ----
  if (wq_active) {
    us8 bh[2][2];
#pragma unroll
    for (int nt = 0; nt < 2; ++nt)
      bh[0][nt] = *(const us8*)(Qhb + (size_t)(wid * 32 + nt * 16 + lm) * DD + g * 8);
#pragma unroll
    for (int kk = 0; kk < 8; ++kk) {
      const int cur = kk & 1, nxt = cur ^ 1;
      if (kk < 7) {
#pragma unroll
        for (int nt = 0; nt < 2; ++nt)
          bh[nxt][nt] = *(const us8*)(Qhb + (size_t)(wid * 32 + nt * 16 + lm) * DD +
                                      (kk + 1) * 32 + g * 8);
      }
      us8 ah[4];
#pragma unroll
      for (int mt = 0; mt < 4; ++mt) {
        const int row = mt * 16 + lm;
        ah[mt] = *(const us8*)(bufC + row * 512 + swz(row, kk * 64 + g * 16));
      }
#pragma unroll
      for (int mt = 0; mt < 4; ++mt)
#pragma unroll
        for (int nt = 0; nt < 2; ++nt)
          acc[mt][nt] = mfmah(ah[mt], bh[cur][nt], acc[mt][nt]);
    }
  }

  // ---- mask (exact fp32 absorption to -1e29, as reference) ----
#pragma unroll
  for (int nt = 0; nt < 2; ++nt) {
    const int q = wid * 32 + nt * 16 + lm;
    const bool qm = q >= qlen;
#pragma unroll
    for (int mt = 0; mt < 4; ++mt)
#pragma unroll
      for (int j = 0; j < 4; ++j) {
        const int c = c0 + mt * 16 + g * 4 + j;
        if (qm || c >= clen) acc[mt][nt][j] = VNEG;
      }
  }

  // ---- per-wave row maxima -> redM ----
#pragma unroll
  for (int mt = 0; mt < 4; ++mt)
#pragma unroll
    for (int j = 0; j < 4; ++j) {
      float m = fmaxf(acc[mt][0][j], acc[mt][1][j]);
      m = fmaxf(m, __shfl_xor(m, 1, 64));
      m = fmaxf(m, __shfl_xor(m, 2, 64));
      m = fmaxf(m, __shfl_xor(m, 4, 64));
      m = fmaxf(m, __shfl_xor(m, 8, 64));
      if (lm == 0) redM[wid * 64 + mt * 16 + g * 4 + j] = m;
    }
  __syncthreads();   // bar2 (redM complete)

  // ---- global row maxima -> wred (first 64 threads) ----
  if (tid < 64) {
    float m = redM[tid];
#pragma unroll
    for (int w = 1; w < 8; ++w) m = fmaxf(m, redM[w * 64 + tid]);
    wred[tid] = m;
  }
  __syncthreads();   // bar3 (wred visible)

  // ---- exp + per-wave row sums -> redS (row max read from LDS) ----
#pragma unroll
  for (int mt = 0; mt < 4; ++mt)
#pragma unroll
    for (int j = 0; j < 4; ++j) {
      const float m = wred[mt * 16 + g * 4 + j];
      float s = 0.f;
#pragma unroll
      for (int nt = 0; nt < 2; ++nt) {
        const float p = __expf(acc[mt][nt][j] - m);
        acc[mt][nt][j] = p;
        s += p;
      }
      s += __shfl_xor(s, 1, 64);
      s += __shfl_xor(s, 2, 64);
      s += __shfl_xor(s, 4, 64);
      s += __shfl_xor(s, 8, 64);
      if (lm == 0) redS[wid * 64 + mt * 16 + g * 4 + j] = s;
    }
  // ---- tile max + wexp + ptM/ptD (wave 0; wred stable after bar3) ----
  if (wid == 0) {
    float m = wred[l];
    m = fmaxf(m, __shfl_xor(m, 1, 64));  m = fmaxf(m, __shfl_xor(m, 2, 64));
    m = fmaxf(m, __shfl_xor(m, 4, 64));  m = fmaxf(m, __shfl_xor(m, 8, 64));
    m = fmaxf(m, __shfl_xor(m, 16, 64)); m = fmaxf(m, __shfl_xor(m, 32, 64));
    const float wv = __expf(wred[l] - m);
    wexp[l] = wv;
    float s = wv;
    s += __shfl_xor(s, 1, 64);  s += __shfl_xor(s, 2, 64);
    s += __shfl_xor(s, 4, 64);  s += __shfl_xor(s, 8, 64);
    s += __shfl_xor(s, 16, 64); s += __shfl_xor(s, 32, 64);
    if (l == 0) { ptD[b * 32 + tile] = s; ptM[b * 32 + tile] = m; }
  }
  __syncthreads();   // bar4 (redS + wexp visible)

  // ---- per-row 1/sum -> sinv ----
  if (tid < 64) {
    float s = 0.f;
#pragma unroll
    for (int w = 0; w < 8; ++w) s += redS[w * 64 + tid];
    sinv[tid] = 1.0f / s;
  }

  // ---- q2c partial from LDS C-tile (wexp==0 for rows >= clen) ----
  {
    const int half = tid >> 8;               // 0/1 -> rows 0..31 / 32..63
    const int d = tid & 255;
    float qacc = 0.f;
    const int d2 = d * 2;
#pragma unroll 8
    for (int r = half * 32; r < half * 32 + 32; ++r) {
      const float cv = h2f(*(const unsigned short*)(bufC + r * 512 + swz(r, d2)));
      qacc += wexp[r] * cv;
    }
    pnum[(((size_t)b * 32 + tile) * 2 + half) * DD + d] = qacc;
  }
  __syncthreads();   // bar5 (bufC reads done; safe to overwrite with P)

  // ---- write P (un-normalized exp, fp16); only strips PV will read ----
  if (wq_active) {
#pragma unroll
    for (int mt = 0; mt < 4; ++mt)
#pragma unroll
      for (int nt = 0; nt < 2; ++nt)
#pragma unroll
        for (int j = 0; j < 4; ++j) {
          const int row = mt * 16 + g * 4 + j;
          const int cb = (wid * 32 + nt * 16 + lm) * 2;
          *(unsigned short*)(bufP + row * 512 + swz(row, cb)) = f2h(acc[mt][nt][j]);
        }
  }
  __syncthreads();   // bar6 (P + sinv visible)

  // ---- preload PV QT fragments for kq < kqmax (static reg indices) ----
  us8 qt[16];
#pragma unroll
  for (int kq = 0; kq < 8; ++kq) {
    if (kq < kqmax) {
#pragma unroll
      for (int dt = 0; dt < 2; ++dt)
        qt[kq * 2 + dt] = *(const us8*)(QTb +
            (size_t)(wid * 32 + dt * 16 + lm) * TQ + kq * 32 + g * 8);
    }
  }

  // ---- PV: truncated at kqmax (P == 0 beyond qlen for valid rows) ----
  f32x4 pacc[4][2];
#pragma unroll
  for (int mt = 0; mt < 4; ++mt)
#pragma unroll
    for (int dt = 0; dt < 2; ++dt) pacc[mt][dt] = (f32x4)0.0f;
#pragma unroll
  for (int kq = 0; kq < 8; ++kq) {
    if (kq < kqmax) {
      us8 pa[4];
#pragma unroll
      for (int mt = 0; mt < 4; ++mt) {
        const int row = mt * 16 + lm;
        pa[mt] = *(const us8*)(bufP + row * 512 + swz(row, kq * 64 + g * 16));
      }
#pragma unroll
      for (int mt = 0; mt < 4; ++mt)
#pragma unroll
        for (int dt = 0; dt < 2; ++dt)
          pacc[mt][dt] = mfmah(pa[mt], qt[kq * 2 + dt], pacc[mt][dt]);
    }
  }

  // ---- epilogue: normalize; rows >= clen get exact qmean ----
  float qv[2];
  if (clen < c0 + CR) {
#pragma unroll
    for (int dt = 0; dt < 2; ++dt)
      qv[dt] = qmean[b * DD + wid * 32 + dt * 16 + lm];
  }
#pragma unroll
  for (int mt = 0; mt < 4; ++mt)
#pragma unroll
    for (int j = 0; j < 4; ++j) {
      const int row = mt * 16 + g * 4 + j;
      const float inv = sinv[row];
      const bool valid = (c0 + row) < clen;
      const size_t rowoff = (size_t)(b * TC + c0 + row) * DD;
#pragma unroll
      for (int dt = 0; dt < 2; ++dt)
        out1[rowoff + wid * 32 + dt * 16 + lm] =
            valid ? pacc[mt][dt][j] * inv : qv[dt];
    }
}

// ---------------------------------------------------------------------------
// kC (fused combine + broadcast): each block recomputes
//   q2c[b,d] = sum_t e^{ptM_t-m}(pnum[t,0,d]+pnum[t,1,d]) / sum_t e^{ptM_t-m} ptD_t
// then broadcasts into its 128-row segment of out2.
// ---------------------------------------------------------------------------
__global__ void kC(const float* __restrict__ pnum, const float* __restrict__ ptM,
                   const float* __restrict__ ptD, float* __restrict__ out2)
{
  const int b = blockIdx.x >> 4, seg = blockIdx.x & 15;
  const int d = threadIdx.x;
  __shared__ float sM[32], sD[32];
  if (d < 32) { sM[d] = ptM[b * 32 + d]; sD[d] = ptD[b * 32 + d]; }
  __syncthreads();
  float m = sM[0];
#pragma unroll
  for (int t = 1; t < 32; ++t) m = fmaxf(m, sM[t]);
  float den = 0.f, acc = 0.f;
#pragma unroll
  for (int t = 0; t < 32; ++t) {
    const float sc = __expf(sM[t] - m);
    den += sc * sD[t];
    const size_t base = (((size_t)b * 32 + t) * 2) * DD + d;
    acc += sc * (pnum[base] + pnum[base + DD]);
  }
  const float s = acc / den;
  float* dst = out2 + ((size_t)b * TC + seg * 128) * DD + d;
#pragma unroll 4
  for (int c = 0; c < 128; ++c) dst[(size_t)c * DD] = s;
}

extern "C" void kernel_launch(void* const* d_in, const int* in_sizes, int n_in,
                              void* d_out, int out_size, void* d_ws, size_t ws_size,
                              hipStream_t stream)
{
  const float* Cg = (const float*)d_in[0];
  const float* Qg = (const float*)d_in[1];
  const int* clen = (const int*)d_in[2];
  const int* qlen = (const int*)d_in[3];
  float* out1 = (float*)d_out;
  float* out2 = out1 + (size_t)NB * TC * DD;

  char* ws = (char*)d_ws;
  float* pnum  = (float*)(ws);                         // 32*32*2*256 f32 = 2 MB
  float* ptM   = (float*)(ws + 2097152);               // 1024 f32
  float* ptD   = (float*)(ws + 2101248);               // 1024 f32
  float* qmean = (float*)(ws + 2105344);               // 32*256 f32 = 32 KB
  unsigned short* Qh = (unsigned short*)(ws + 2138112);          // 4 MB
  unsigned short* QT = (unsigned short*)(ws + 2138112 + 4194304);// 4 MB

  P0 <<<dim3(544), dim3(256), 0, stream>>>(Qg, Qh, QT, qmean);
  kA <<<dim3(NB * (TC / CR)), dim3(512), 0, stream>>>(Cg, Qh, QT, qmean,
                                                      clen, qlen,
                                                      out1, pnum, ptM, ptD);
  kC <<<dim3(NB * 16), dim3(256), 0, stream>>>(pnum, ptM, ptD, out2);
}